// Round 4
// baseline (109.903 us; speedup 1.0000x reference)
//
#include <hip/hip_runtime.h>

#define BD 4096   // rows
#define CD 256    // codes
#define DD 128    // dim
#define ROWS 4    // rows per block -> grid 1024; VGPR<=128 -> 4 blocks/CU = 16 waves/CU
#define CT 32     // codes per LDS tile (8 tiles) -> ~23.5 KB LDS incl. runtime overhead
#define NT (CD / CT)
#define PAD 132   // padded LDS row stride in floats (16B-aligned; breaks 128-float banking)

__global__ __launch_bounds__(256, 4) void rq_fused(
    const float* __restrict__ x,
    const float* __restrict__ pq,
    const float* __restrict__ codes,
    float* __restrict__ out)   // [quantized BD*DD | indices BD | loss 1]
{
    __shared__ float xc_s[ROWS * PAD];
    __shared__ float code_s[CT * PAD];
    __shared__ float row_c[ROWS], row_s[ROWS], row_invn[ROWS];
    __shared__ int   row_idx[ROWS];
    __shared__ float red_v[ROWS * 4];   // [row][wave] argmin candidates
    __shared__ int   red_i[ROWS * 4];
    __shared__ float loss_s[ROWS];

    const int tid  = threadIdx.x;
    const int wv   = tid >> 6;
    const int lane = tid & 63;
    const int row0 = blockIdx.x * ROWS;
    const float INV_SQRT_D = 0.088388347648318447f;  // 1/sqrt(128)

    // ---------- Phase A: per-row rotation  xc = R^T x (rank-2 form) ----------
    // wave wv handles row wv; each lane holds 2 elements (float2).
    {
        const int r = wv;
        const size_t grow = (size_t)(row0 + r);
        const float2 xv = ((const float2*)(x  + grow * DD))[lane];
        const float2 pv = ((const float2*)(pq + grow * DD))[lane];
        float s0 = pv.x * pv.x + pv.y * pv.y;   // ||pq||^2
        float s1 = pv.x + pv.y;                 // sum pq
        float s2 = xv.x + xv.y;                 // sum x
        float s3 = pv.x * xv.x + pv.y * xv.y;   // pq . x
        #pragma unroll
        for (int m = 32; m > 0; m >>= 1) {
            s0 += __shfl_xor(s0, m);
            s1 += __shfl_xor(s1, m);
            s2 += __shfl_xor(s2, m);
            s3 += __shfl_xor(s3, m);
        }
        const float invn = 1.0f / fmaxf(sqrtf(s0), 1e-6f);  // u = pq * invn
        const float b = s2 * INV_SQRT_D;                    // v.x
        const float a = s3 * invn;                          // u.x
        const float c = s1 * invn * INV_SQRT_D;             // u.v
        const float s = 1.0f / (1.0f + c + 1e-6f);
        // R^T x = x + u*(-b + s(cb - a)) + v*(a + s(ca - b))
        const float au = -b + s * (c * b - a);
        const float av =  a + s * (c * a - b);
        xc_s[r * PAD + 2 * lane]     = xv.x + au * (pv.x * invn) + av * INV_SQRT_D;
        xc_s[r * PAD + 2 * lane + 1] = xv.y + au * (pv.y * invn) + av * INV_SQRT_D;
        if (lane == 0) { row_c[r] = c; row_s[r] = s; row_invn[r] = invn; }
    }

    // ---------- Phase B: distances + argmin ----------
    // wave tile = 4 rows x 8 codes x 2 D-halves; thread -> (row lr, code wv*8+lc, half lcD)
    const int lc  = lane & 7;          // code-in-wave 0..7
    const int lcD = (lane >> 3) & 1;   // D half 0..1
    const int lr  = lane >> 4;         // row 0..3
    float bestv = 3.4e38f;
    int   besti = 0;

    // register prefetch: tile = CT*DD/4 = 1024 float4; 4 float4/thread
    float4 pf[4];
    {
        const float4* src = (const float4*)codes;
        #pragma unroll
        for (int k = 0; k < 4; ++k) pf[k] = src[k * 256 + tid];
    }

    for (int t = 0; t < NT; ++t) {
        __syncthreads();   // t=0: xc_s ready; t>0: prev compute done, code_s free
        #pragma unroll
        for (int k = 0; k < 4; ++k) {
            const int f = k * 256 + tid;                 // [0,1024)
            *(float4*)(code_s + (f >> 5) * PAD + (f & 31) * 4) = pf[k];
        }
        __syncthreads();
        if (t + 1 < NT) {   // prefetch next tile during compute
            const float4* src = ((const float4*)codes) + (size_t)(t + 1) * (CT * DD / 4);
            #pragma unroll
            for (int k = 0; k < 4; ++k) pf[k] = src[k * 256 + tid];
        }

        const int cit = wv * 8 + lc;                     // code index within tile [0,32)
        const float* xr = xc_s   + lr  * PAD + lcD * 64;
        const float* cr = code_s + cit * PAD + lcD * 64;
        float acc0 = 0.f, acc1 = 0.f;
        #pragma unroll
        for (int d4 = 0; d4 < 16; ++d4) {                // 64 floats = this thread's half
            const float4 xa = *(const float4*)(xr + d4 * 4);
            const float4 va = *(const float4*)(cr + d4 * 4);
            float dx;
            dx = xa.x - va.x; acc0 = fmaf(dx, dx, acc0);
            dx = xa.y - va.y; acc1 = fmaf(dx, dx, acc1);
            dx = xa.z - va.z; acc0 = fmaf(dx, dx, acc0);
            dx = xa.w - va.w; acc1 = fmaf(dx, dx, acc1);
        }
        float dsum = acc0 + acc1;
        dsum += __shfl_xor(dsum, 8);                     // combine the two D halves
        const int ci = t * CT + cit;
        if (dsum < bestv) { bestv = dsum; besti = ci; }  // t ascends -> first-min kept
    }

    // reduce argmin over the 16 lanes of this row's lane group (halves hold identical copies)
    #pragma unroll
    for (int m = 8; m > 0; m >>= 1) {
        const float ov = __shfl_xor(bestv, m);
        const int   oi = __shfl_xor(besti, m);
        if (ov < bestv || (ov == bestv && oi < besti)) { bestv = ov; besti = oi; }
    }
    if ((lane & 15) == 0) { red_v[lr * 4 + wv] = bestv; red_i[lr * 4 + wv] = besti; }
    __syncthreads();
    if (tid < ROWS) {   // thread r finalizes row r across the 4 waves
        float bv = red_v[tid * 4];
        int   bi = red_i[tid * 4];
        #pragma unroll
        for (int w = 1; w < 4; ++w) {
            const float ov = red_v[tid * 4 + w];
            const int   oi = red_i[tid * 4 + w];
            if (ov < bv || (ov == bv && oi < bi)) { bv = ov; bi = oi; }
        }
        row_idx[tid] = bi;
        out[(size_t)BD * DD + row0 + tid] = (float)bi;
    }
    __syncthreads();

    // ---------- Phase C: quantized = R * codes[idx] (rank-2), + loss ----------
    // wave wv = row wv; each lane handles 2 elements (float2)
    {
        const int r = wv;
        const int qi = row_idx[r];
        const float invn = row_invn[r];
        const float c = row_c[r];
        const float s = row_s[r];
        const size_t grow = (size_t)(row0 + r);
        const float2 q = ((const float2*)(codes + (size_t)qi * DD))[lane];
        const float2 p = ((const float2*)(pq + grow * DD))[lane];
        float pd = p.x * q.x + p.y * q.y;
        float ws = q.x + q.y;
        #pragma unroll
        for (int m = 32; m > 0; m >>= 1) {
            pd += __shfl_xor(pd, m);
            ws += __shfl_xor(ws, m);
        }
        const float pp = pd * invn;          // u . q
        const float w  = ws * INV_SQRT_D;    // v . q
        // R q = q + u*(w + s(cw - p)) + v*(-p + s(cp - w))
        const float bu =  w + s * (c * w - pp);
        const float bv = -pp + s * (c * pp - w);
        float2 o;
        o.x = q.x + bu * (p.x * invn) + bv * INV_SQRT_D;
        o.y = q.y + bu * (p.y * invn) + bv * INV_SQRT_D;
        ((float2*)(out + grow * DD))[lane] = o;

        const float2 xv = ((const float2*)(x + grow * DD))[lane];
        float dx = xv.x - o.x;
        float ls = dx * dx;
        dx = xv.y - o.y;
        ls = fmaf(dx, dx, ls);
        #pragma unroll
        for (int m = 32; m > 0; m >>= 1) ls += __shfl_xor(ls, m);
        if (lane == 0) loss_s[r] = ls;
    }
    __syncthreads();
    if (tid == 0) {
        const float tot = loss_s[0] + loss_s[1] + loss_s[2] + loss_s[3];
        // loss = loss_commit + 0.25*loss_codebook = 1.25 * mean_b ||x - q||^2
        atomicAdd(out + (size_t)BD * DD + BD, tot * (1.25f / (float)BD));
    }
}

extern "C" void kernel_launch(void* const* d_in, const int* in_sizes, int n_in,
                              void* d_out, int out_size, void* d_ws, size_t ws_size,
                              hipStream_t stream) {
    const float* xin   = (const float*)d_in[0];
    const float* prevq = (const float*)d_in[1];
    const float* codes = (const float*)d_in[2];
    float* out = (float*)d_out;
    // zero the loss accumulator slot (harness poisons d_out with 0xAA)
    hipMemsetAsync((void*)(out + (size_t)BD * DD + BD), 0, sizeof(float), stream);
    rq_fused<<<BD / ROWS, 256, 0, stream>>>(xin, prevq, codes, out);
}